// Round 1
// baseline (1775.079 us; speedup 1.0000x reference)
//
#include <hip/hip_runtime.h>
#include <stdint.h>

#define B_ 4
#define T_ 2048
#define D_ 1024
#define M_ (B_*T_)          // 8192 rows (b,t)
#define NGRAM_ 3
#define BR_ 4
#define BUCKET_ 100000
#define LN_EPS_ 1e-5f

typedef __attribute__((ext_vector_type(8))) short short8;
typedef __attribute__((ext_vector_type(4))) float f32x4;

// ---------- helpers ----------
__device__ __forceinline__ unsigned short f2bf(float f) {
  unsigned u = __float_as_uint(f);
  u += 0x7fffu + ((u >> 16) & 1u);   // RNE (finite values only here)
  return (unsigned short)(u >> 16);
}
__device__ __forceinline__ float bf2f(unsigned short s) {
  return __uint_as_float(((unsigned)s) << 16);
}

// block of 256 threads (4 waves); returns full sum to all threads
__device__ __forceinline__ float block_sum256(float v, float* sm) {
  #pragma unroll
  for (int o = 32; o; o >>= 1) v += __shfl_down(v, o, 64);
  __syncthreads();                       // protect sm from previous use
  if ((threadIdx.x & 63) == 0) sm[threadIdx.x >> 6] = v;
  __syncthreads();
  return (sm[0] + sm[1]) + (sm[2] + sm[3]);
}

// ---------- kernel 1: clip+LN hidden, gather+LN embeddings ----------
__global__ __launch_bounds__(256) void prep_kernel(
    const float* __restrict__ hidden, const int* __restrict__ buckets,
    const float* __restrict__ tables,
    unsigned short* __restrict__ h_norm, unsigned short* __restrict__ e_norm)
{
  __shared__ float sm[4];
  const int r = blockIdx.x, tid = threadIdx.x;

  float4 x = ((const float4*)(hidden + (size_t)r * D_))[tid];
  x.x = fminf(fmaxf(x.x, -10.f), 10.f);
  x.y = fminf(fmaxf(x.y, -10.f), 10.f);
  x.z = fminf(fmaxf(x.z, -10.f), 10.f);
  x.w = fminf(fmaxf(x.w, -10.f), 10.f);
  float mean = block_sum256(x.x + x.y + x.z + x.w, sm) * (1.f / D_);
  float a0 = x.x - mean, a1 = x.y - mean, a2 = x.z - mean, a3 = x.w - mean;
  float var = block_sum256(a0*a0 + a1*a1 + a2*a2 + a3*a3, sm) * (1.f / D_);
  float rstd = rsqrtf(var + LN_EPS_);
  ushort4 p;
  p.x = f2bf(a0 * rstd); p.y = f2bf(a1 * rstd);
  p.z = f2bf(a2 * rstd); p.w = f2bf(a3 * rstd);
  ((ushort4*)(h_norm + (size_t)r * D_))[tid] = p;

  #pragma unroll
  for (int n = 0; n < NGRAM_; ++n) {
    int bk = buckets[(size_t)n * M_ + r];
    float4 e = ((const float4*)(tables + ((size_t)n * BUCKET_ + bk) * D_))[tid];
    float em = block_sum256(e.x + e.y + e.z + e.w, sm) * (1.f / D_);
    float b0 = e.x - em, b1 = e.y - em, b2 = e.z - em, b3 = e.w - em;
    float ev = block_sum256(b0*b0 + b1*b1 + b2*b2 + b3*b3, sm) * (1.f / D_);
    float ers = rsqrtf(ev + LN_EPS_);
    ushort4 q;
    q.x = f2bf(b0 * ers); q.y = f2bf(b1 * ers);
    q.z = f2bf(b2 * ers); q.w = f2bf(b3 * ers);
    ((ushort4*)(e_norm + ((size_t)n * M_ + r) * D_))[tid] = q;
  }
}

// ---------- kernel 1b: cast W_K / W_V to bf16 ----------
__global__ __launch_bounds__(256) void convw_kernel(
    const float* __restrict__ wk, const float* __restrict__ wv,
    unsigned short* __restrict__ wk_b, unsigned short* __restrict__ wv_b)
{
  const int nk = (BR_ * NGRAM_ * D_ * D_) / 4;   // 3145728 quads
  int idx = blockIdx.x * 256 + threadIdx.x;
  float4 v; ushort4 p;
  if (idx < nk) {
    v = ((const float4*)wk)[idx];
    p.x = f2bf(v.x); p.y = f2bf(v.y); p.z = f2bf(v.z); p.w = f2bf(v.w);
    ((ushort4*)wk_b)[idx] = p;
  } else {
    int j = idx - nk;
    v = ((const float4*)wv)[j];
    p.x = f2bf(v.x); p.y = f2bf(v.y); p.z = f2bf(v.z); p.w = f2bf(v.w);
    ((ushort4*)wv_b)[j] = p;
  }
}

// ---------- shared GEMM mainloop: C[t,o] = sum_d A[t,d]*Bm[o,d] ----------
// 128x128 tile, BK=64, 4 waves in 2x2, each wave 64x64 via 4x4 of 16x16x32 MFMA.
// LDS rows padded to 72 shorts (breaks power-of-2 bank strides, keeps 16B align).
#define LDS_STRIDE 72

__device__ __forceinline__ void gemm_mainloop(
    const unsigned short* __restrict__ A, const unsigned short* __restrict__ Bm,
    unsigned short* a_lds, unsigned short* b_lds,
    f32x4 acc[4][4], int arow0, int brow0)
{
  const int tid = threadIdx.x;
  const int lane = tid & 63;
  const int wid = tid >> 6;
  const int wm = wid & 1, wn = wid >> 1;

  short8 ra[4], rb[4];
  // prefetch kt=0
  #pragma unroll
  for (int c = 0; c < 4; ++c) {
    int ch = c * 256 + tid;
    int row = ch >> 3, q = ch & 7;
    ra[c] = *(const short8*)&A[(size_t)(arow0 + row) * D_ + q * 8];
    rb[c] = *(const short8*)&Bm[(size_t)(brow0 + row) * D_ + q * 8];
  }

  for (int kt = 0; kt < 16; ++kt) {
    __syncthreads();   // previous iteration's readers done
    #pragma unroll
    for (int c = 0; c < 4; ++c) {
      int ch = c * 256 + tid;
      int row = ch >> 3, q = ch & 7;
      *(short8*)&a_lds[row * LDS_STRIDE + q * 8] = ra[c];
      *(short8*)&b_lds[row * LDS_STRIDE + q * 8] = rb[c];
    }
    __syncthreads();
    if (kt < 15) {    // prefetch next K-tile while computing this one
      #pragma unroll
      for (int c = 0; c < 4; ++c) {
        int ch = c * 256 + tid;
        int row = ch >> 3, q = ch & 7;
        ra[c] = *(const short8*)&A[(size_t)(arow0 + row) * D_ + (kt + 1) * 64 + q * 8];
        rb[c] = *(const short8*)&Bm[(size_t)(brow0 + row) * D_ + (kt + 1) * 64 + q * 8];
      }
    }
    #pragma unroll
    for (int kk = 0; kk < 2; ++kk) {
      short8 af[4], bfv[4];
      const int q = kk * 4 + (lane >> 4);
      #pragma unroll
      for (int i = 0; i < 4; ++i) {
        af[i]  = *(const short8*)&a_lds[(wm * 64 + i * 16 + (lane & 15)) * LDS_STRIDE + q * 8];
        bfv[i] = *(const short8*)&b_lds[(wn * 64 + i * 16 + (lane & 15)) * LDS_STRIDE + q * 8];
      }
      #pragma unroll
      for (int i = 0; i < 4; ++i)
        #pragma unroll
        for (int j = 0; j < 4; ++j)
          acc[i][j] = __builtin_amdgcn_mfma_f32_16x16x32_bf16(af[i], bfv[j], acc[i][j], 0, 0, 0);
    }
  }
}

// ---------- kernel 2: GEMM + fused LN-score reductions ----------
// grid (64 m-tiles, 8 o-tiles, 12 = n*4+m). accs[z][row][0..2] = sum k, sum k^2, sum h*k
__global__ __launch_bounds__(256, 2) void gemm_score_kernel(
    const unsigned short* __restrict__ e_norm, const unsigned short* __restrict__ wk_b,
    const unsigned short* __restrict__ h_norm, float* __restrict__ accs)
{
  __shared__ unsigned short a_lds[128 * LDS_STRIDE];
  __shared__ unsigned short b_lds[128 * LDS_STRIDE];
  const int z = blockIdx.z;
  const int n = z >> 2, m = z & 3;
  const unsigned short* A  = e_norm + (size_t)n * M_ * D_;
  const unsigned short* Bm = wk_b + (size_t)(m * NGRAM_ + n) * D_ * D_;

  f32x4 acc[4][4];
  #pragma unroll
  for (int i = 0; i < 4; ++i)
    #pragma unroll
    for (int j = 0; j < 4; ++j)
      acc[i][j] = (f32x4){0.f, 0.f, 0.f, 0.f};

  gemm_mainloop(A, Bm, a_lds, b_lds, acc, blockIdx.x * 128, blockIdx.y * 128);

  const int lane = threadIdx.x & 63;
  const int wid = threadIdx.x >> 6, wm = wid & 1, wn = wid >> 1;
  const int cg = lane >> 4, cc = lane & 15;
  float* az = accs + (size_t)z * M_ * 4;
  #pragma unroll
  for (int i = 0; i < 4; ++i) {
    #pragma unroll
    for (int rg = 0; rg < 4; ++rg) {
      int row_g = blockIdx.x * 128 + wm * 64 + i * 16 + cg * 4 + rg;
      float s1 = 0.f, s2 = 0.f, s3 = 0.f;
      #pragma unroll
      for (int j = 0; j < 4; ++j) {
        int col_g = blockIdx.y * 128 + wn * 64 + j * 16 + cc;
        float kv = acc[i][j][rg];
        float hv = bf2f(h_norm[(size_t)row_g * D_ + col_g]);
        s1 += kv; s2 += kv * kv; s3 += hv * kv;
      }
      #pragma unroll
      for (int o = 8; o; o >>= 1) {
        s1 += __shfl_xor(s1, o, 64);
        s2 += __shfl_xor(s2, o, 64);
        s3 += __shfl_xor(s3, o, 64);
      }
      if (cc == 0) {
        atomicAdd(&az[row_g * 4 + 0], s1);
        atomicAdd(&az[row_g * 4 + 1], s2);
        atomicAdd(&az[row_g * 4 + 2], s3);
      }
    }
  }
}

// ---------- kernel 3: gates + fused embedding blend ----------
__global__ __launch_bounds__(256) void fuse_kernel(
    const int* __restrict__ buckets, const float* __restrict__ tables,
    const float* __restrict__ accs, unsigned short* __restrict__ fused)
{
  const int r = blockIdx.x, tid = threadIdx.x;
  float gw[NGRAM_]; float gsum = 0.f;
  #pragma unroll
  for (int n = 0; n < NGRAM_; ++n) {
    float g = 0.f;
    #pragma unroll
    for (int m = 0; m < BR_; ++m) {
      const float* a = accs + ((size_t)(n * 4 + m) * M_ + r) * 4;
      float s1 = a[0], s2 = a[1], s3 = a[2];
      float mean = s1 * (1.f / D_);
      float var = s2 * (1.f / D_) - mean * mean;
      float score = s3 * rsqrtf(var + LN_EPS_) * (1.f / 32.f);
      score = fminf(fmaxf(score, -10.f), 10.f);
      g += 1.f / (1.f + __expf(-score));
    }
    g *= 0.25f;
    float w = 1.f + 0.3f * n;
    gw[n] = g * w;
    gsum += g * w;
  }
  float inv = 1.f / (gsum + 1e-8f);

  float4 v0 = ((const float4*)(tables + ((size_t)0 * BUCKET_ + buckets[0 * M_ + r]) * D_))[tid];
  float4 v1 = ((const float4*)(tables + ((size_t)1 * BUCKET_ + buckets[1 * M_ + r]) * D_))[tid];
  float4 v2 = ((const float4*)(tables + ((size_t)2 * BUCKET_ + buckets[2 * M_ + r]) * D_))[tid];
  ushort4 p;
  p.x = f2bf((gw[0] * v0.x + gw[1] * v1.x + gw[2] * v2.x) * inv);
  p.y = f2bf((gw[0] * v0.y + gw[1] * v1.y + gw[2] * v2.y) * inv);
  p.z = f2bf((gw[0] * v0.z + gw[1] * v1.z + gw[2] * v2.z) * inv);
  p.w = f2bf((gw[0] * v0.w + gw[1] * v1.w + gw[2] * v2.w) * inv);
  ((ushort4*)(fused + (size_t)r * D_))[tid] = p;
}

// ---------- kernel 4: V = fused @ W_V^T ----------
__global__ __launch_bounds__(256, 2) void gemm_v_kernel(
    const unsigned short* __restrict__ fused, const unsigned short* __restrict__ wv_b,
    float* __restrict__ V)
{
  __shared__ unsigned short a_lds[128 * LDS_STRIDE];
  __shared__ unsigned short b_lds[128 * LDS_STRIDE];
  f32x4 acc[4][4];
  #pragma unroll
  for (int i = 0; i < 4; ++i)
    #pragma unroll
    for (int j = 0; j < 4; ++j)
      acc[i][j] = (f32x4){0.f, 0.f, 0.f, 0.f};

  gemm_mainloop(fused, wv_b, a_lds, b_lds, acc, blockIdx.x * 128, blockIdx.y * 128);

  const int lane = threadIdx.x & 63;
  const int wid = threadIdx.x >> 6, wm = wid & 1, wn = wid >> 1;
  const int cg = lane >> 4, cc = lane & 15;
  #pragma unroll
  for (int i = 0; i < 4; ++i) {
    #pragma unroll
    for (int rg = 0; rg < 4; ++rg) {
      int row_g = blockIdx.x * 128 + wm * 64 + i * 16 + cg * 4 + rg;
      #pragma unroll
      for (int j = 0; j < 4; ++j) {
        int col_g = blockIdx.y * 128 + wn * 64 + j * 16 + cc;
        V[(size_t)row_g * D_ + col_g] = acc[i][j][rg];
      }
    }
  }
}

// ---------- kernel 5: depthwise conv over T + bias ----------
__global__ __launch_bounds__(256) void conv_kernel(
    const float* __restrict__ V, const float* __restrict__ cw,
    const float* __restrict__ cb, float* __restrict__ out)
{
  int idx = blockIdx.x * 256 + threadIdx.x;     // over B*T*D = 8388608
  int d = idx & (D_ - 1);
  int bt = idx >> 10;
  int t = bt & (T_ - 1);
  float w0 = cw[d * 3 + 0], w1 = cw[d * 3 + 1], w2 = cw[d * 3 + 2];
  float xm = (t > 0)      ? V[idx - D_] : 0.f;
  float xc = V[idx];
  float xp = (t < T_ - 1) ? V[idx + D_] : 0.f;
  out[idx] = cb[d] + w0 * xm + w1 * xc + w2 * xp;
}

// ---------- launch ----------
extern "C" void kernel_launch(void* const* d_in, const int* in_sizes, int n_in,
                              void* d_out, int out_size, void* d_ws, size_t ws_size,
                              hipStream_t stream) {
  const float* hidden = (const float*)d_in[1];
  const int* buckets  = (const int*)d_in[2];
  const float* tables = (const float*)d_in[3];
  const float* W_K    = (const float*)d_in[4];
  const float* W_V    = (const float*)d_in[5];
  const float* conv_w = (const float*)d_in[6];
  const float* conv_b = (const float*)d_in[7];
  float* out = (float*)d_out;

  char* ws = (char*)d_ws;
  unsigned short* h_norm = (unsigned short*)(ws + 0);           // 16,777,216 B
  unsigned short* e_norm = (unsigned short*)(ws + 16777216);    // 50,331,648 B
  unsigned short* wk_b   = (unsigned short*)(ws + 67108864);    // 25,165,824 B
  unsigned short* wv_b   = (unsigned short*)(ws + 92274688);    //  2,097,152 B
  float*          accs   = (float*)(ws + 94371840);             //  1,572,864 B
  unsigned short* fused  = (unsigned short*)(ws + 95944704);    // 16,777,216 B
  float*          V      = (float*)(ws + 112721920);            // 33,554,432 B
  // total 146,276,352 B

  hipMemsetAsync(accs, 0, (size_t)12 * M_ * 4 * sizeof(float), stream);
  prep_kernel<<<M_, 256, 0, stream>>>(hidden, buckets, tables, h_norm, e_norm);
  convw_kernel<<<13312, 256, 0, stream>>>(W_K, W_V, wk_b, wv_b);
  dim3 g1(64, 8, 12);
  gemm_score_kernel<<<g1, 256, 0, stream>>>(e_norm, wk_b, h_norm, accs);
  fuse_kernel<<<M_, 256, 0, stream>>>(buckets, tables, accs, fused);
  dim3 g2(64, 8, 1);
  gemm_v_kernel<<<g2, 256, 0, stream>>>(fused, wv_b, V);
  conv_kernel<<<32768, 256, 0, stream>>>(V, conv_w, conv_b, out);
}